// Round 1
// baseline (10188.741 us; speedup 1.0000x reference)
//
#include <hip/hip_runtime.h>
#include <cstdint>
#include <cstddef>

// Problem constants (from reference): B=32, S=2048, DK=DV=64
#define BATCH 32
#define SEQ   2048
#define DIM   64
#define RQ    8      // q-rows per workgroup (scores held in registers: 8 cols/thread * 8 rows)
#define T     256    // threads per workgroup

// 1/sqrt(512)  (TEMPER = d_model**0.5 = sqrt(512), NOT sqrt(dk))
#define INV_TEMPER 0.044194173824159216f

// --- mask dtype detection ---------------------------------------------------
// jax bool mask may arrive as 1-byte bools or as int32 0/1. For int32 (LE),
// every byte at offset%4 != 0 is zero. For random 0/1 bytes, P(all zero) ~ 2^-3072.
__global__ void detect_mask_kernel(const unsigned char* __restrict__ m, int* __restrict__ flag) {
    if (threadIdx.x == 0) {
        int f = 0;
        for (int i = 0; i < 4096; ++i) {
            if ((i & 3) && m[i]) { f = 1; break; }
        }
        *flag = f;   // 1 => bytes (bool), 0 => int32
    }
}

// --- fused attention: scores -> softmax -> write attn -> PV -----------------
__global__ __launch_bounds__(T)
void attn_kernel(const float* __restrict__ q, const float* __restrict__ k,
                 const float* __restrict__ v, const unsigned char* __restrict__ maskb,
                 const int* __restrict__ flagp,
                 float* __restrict__ outp, float* __restrict__ attnp)
{
    __shared__ __align__(16) float qs[RQ][DIM];   // 2 KB
    __shared__ float red[RQ][T];                  // 8 KB (reductions, reused)
    __shared__ __align__(16) float pch[RQ][T];    // 8 KB (PV p-chunk)

    const int tid = threadIdx.x;
    const int b   = blockIdx.y;
    const int q0  = blockIdx.x * RQ;

    // ---- load Q tile into LDS ----
    for (int idx = tid; idx < RQ * DIM; idx += T) {
        const int r = idx >> 6, d = idx & 63;
        qs[r][d] = q[((size_t)(b * SEQ + q0 + r)) * DIM + d];
    }
    __syncthreads();

    // ---- scores: sc[r][i] = dot(q_row_r, k_col) ; col = i*256 + tid ----
    float sc[RQ][8];
    #pragma unroll
    for (int i = 0; i < 8; ++i) {
        const int col = i * T + tid;
        const float4* kp = (const float4*)(k + ((size_t)(b * SEQ + col)) * DIM);
        float acc[RQ];
        #pragma unroll
        for (int r = 0; r < RQ; ++r) acc[r] = 0.0f;
        #pragma unroll
        for (int c = 0; c < 16; ++c) {
            const float4 kk = kp[c];
            #pragma unroll
            for (int r = 0; r < RQ; ++r) {
                const float4 qq = *(const float4*)&qs[r][c * 4];
                acc[r] = fmaf(qq.x, kk.x, acc[r]);
                acc[r] = fmaf(qq.y, kk.y, acc[r]);
                acc[r] = fmaf(qq.z, kk.z, acc[r]);
                acc[r] = fmaf(qq.w, kk.w, acc[r]);
            }
        }
        #pragma unroll
        for (int r = 0; r < RQ; ++r) sc[r][i] = acc[r];
    }

    // ---- scale + mask ----
    const int boolmask = *flagp;   // wave-uniform
    #pragma unroll
    for (int r = 0; r < RQ; ++r) {
        const size_t mrow = ((size_t)(b * SEQ + q0 + r)) * SEQ;
        #pragma unroll
        for (int i = 0; i < 8; ++i) {
            const size_t moff = mrow + i * T + tid;
            int mv;
            if (boolmask) mv = (int)maskb[moff];
            else          mv = ((const int*)maskb)[moff];
            const float x = sc[r][i] * INV_TEMPER;
            sc[r][i] = mv ? -INFINITY : x;
        }
    }

    // ---- row max (block reduce) ----
    float m[RQ];
    #pragma unroll
    for (int r = 0; r < RQ; ++r) {
        float t = sc[r][0];
        #pragma unroll
        for (int i = 1; i < 8; ++i) t = fmaxf(t, sc[r][i]);
        red[r][tid] = t;
    }
    __syncthreads();
    for (int off = T / 2; off > 0; off >>= 1) {
        if (tid < off) {
            #pragma unroll
            for (int r = 0; r < RQ; ++r)
                red[r][tid] = fmaxf(red[r][tid], red[r][tid + off]);
        }
        __syncthreads();
    }
    #pragma unroll
    for (int r = 0; r < RQ; ++r) m[r] = red[r][0];
    __syncthreads();   // before reusing red

    // ---- exp + row sum (block reduce) ----
    #pragma unroll
    for (int r = 0; r < RQ; ++r) {
        float ts = 0.0f;
        #pragma unroll
        for (int i = 0; i < 8; ++i) {
            const float e = __expf(sc[r][i] - m[r]);
            sc[r][i] = e;
            ts += e;
        }
        red[r][tid] = ts;
    }
    __syncthreads();
    for (int off = T / 2; off > 0; off >>= 1) {
        if (tid < off) {
            #pragma unroll
            for (int r = 0; r < RQ; ++r)
                red[r][tid] += red[r][tid + off];
        }
        __syncthreads();
    }
    float invl[RQ];
    #pragma unroll
    for (int r = 0; r < RQ; ++r) invl[r] = 1.0f / red[r][0];

    // ---- normalize + write attn (coalesced) ----
    #pragma unroll
    for (int r = 0; r < RQ; ++r) {
        const size_t base = ((size_t)(b * SEQ + q0 + r)) * SEQ;
        #pragma unroll
        for (int i = 0; i < 8; ++i) {
            const float p = sc[r][i] * invl[r];
            sc[r][i] = p;
            attnp[base + i * T + tid] = p;
        }
    }

    // ---- PV: out[r][d] = sum_col p[r][col] * v[col][d] ----
    const int d   = tid & 63;
    const int sub = tid >> 6;      // 4 sub-groups split the 256-col chunk
    float oa[RQ];
    #pragma unroll
    for (int r = 0; r < RQ; ++r) oa[r] = 0.0f;

    for (int i = 0; i < 8; ++i) {
        __syncthreads();           // protect pch reuse across chunks
        #pragma unroll
        for (int r = 0; r < RQ; ++r) pch[r][tid] = sc[r][i];   // pch[r][t] = p for col i*256+t
        __syncthreads();

        const float* vbase = v + ((size_t)(b * SEQ + i * T + sub * 64)) * DIM + d;
        #pragma unroll
        for (int c4 = 0; c4 < 16; ++c4) {
            const float vv0 = vbase[(c4 * 4 + 0) * DIM];
            const float vv1 = vbase[(c4 * 4 + 1) * DIM];
            const float vv2 = vbase[(c4 * 4 + 2) * DIM];
            const float vv3 = vbase[(c4 * 4 + 3) * DIM];
            #pragma unroll
            for (int r = 0; r < RQ; ++r) {
                const float4 pp = *(const float4*)&pch[r][sub * 64 + c4 * 4];
                float a = oa[r];
                a = fmaf(pp.x, vv0, a);
                a = fmaf(pp.y, vv1, a);
                a = fmaf(pp.z, vv2, a);
                a = fmaf(pp.w, vv3, a);
                oa[r] = a;
            }
        }
    }

    // ---- reduce the 4 sub-group partials, write output ----
    __syncthreads();
    #pragma unroll
    for (int r = 0; r < RQ; ++r) red[r][tid] = oa[r];
    __syncthreads();
    if (sub == 0) {
        #pragma unroll
        for (int r = 0; r < RQ; ++r) {
            const float s = red[r][d] + red[r][64 + d] + red[r][128 + d] + red[r][192 + d];
            outp[((size_t)(b * SEQ + q0 + r)) * DIM + d] = s;
        }
    }
}

extern "C" void kernel_launch(void* const* d_in, const int* in_sizes, int n_in,
                              void* d_out, int out_size, void* d_ws, size_t ws_size,
                              hipStream_t stream) {
    const float* q = (const float*)d_in[0];
    const float* k = (const float*)d_in[1];
    const float* v = (const float*)d_in[2];
    const unsigned char* mask = (const unsigned char*)d_in[3];

    float* outp  = (float*)d_out;                                  // [B,S,DIM]
    float* attnp = outp + (size_t)BATCH * SEQ * DIM;               // [B,S,S]
    int* flag = (int*)d_ws;

    hipLaunchKernelGGL(detect_mask_kernel, dim3(1), dim3(64), 0, stream, mask, flag);

    dim3 grid(SEQ / RQ, BATCH);
    hipLaunchKernelGGL(attn_kernel, grid, dim3(T), 0, stream,
                       q, k, v, mask, flag, outp, attnp);
}